// Round 12
// baseline (486.382 us; speedup 1.0000x reference)
//
#include <hip/hip_runtime.h>

typedef unsigned short ushort_t;
typedef unsigned int uint_t;

using bf16x8 = __attribute__((ext_vector_type(8))) short;
using f32x4  = __attribute__((ext_vector_type(4))) float;

// ---------- helpers ----------
__device__ __forceinline__ ushort_t f2b(float f){
    union { float f; uint_t u; } v; v.f = f;
    uint_t u = v.u;
    uint_t r = (u + 0x7FFFu + ((u >> 16) & 1u)) >> 16;   // RNE
    return (ushort_t)r;
}

// ---------- weight prep: f32 -> bf16 (+ conv restride) + x transpose ----------
__global__ void prep_k(const float* __restrict__ vW, const float* __restrict__ Wx,
                       const float* __restrict__ Wh, const float* __restrict__ cW,
                       const float* __restrict__ sW, const float* __restrict__ oW,
                       const float* __restrict__ pW, const float* __restrict__ x,
                       ushort_t* __restrict__ wb, float* __restrict__ xT)
{
    int idx = blockIdx.x * 256 + threadIdx.x;
    switch (blockIdx.y){
    case 0: if (idx < 16384) wb[idx]          = f2b(vW[idx]);           break;
    case 1: if (idx < 65536) wb[16384  + idx] = f2b(Wx[idx]);           break; // Wx0
    case 2: if (idx < 65536) wb[81920  + idx] = f2b(Wh[idx]);           break; // Wh0
    case 3: if (idx < 65536) wb[147456 + idx] = f2b(Wx[65536 + idx]);   break; // Wx1
    case 4: if (idx < 65536) wb[212992 + idx] = f2b(Wh[65536 + idx]);   break; // Wh1
    case 5: if (idx < 49152){                                                  // conv [k][o][i]
                int k = idx >> 14; int oi = idx & 16383;
                wb[278528 + idx] = f2b(cW[oi * 3 + k]);
            } break;
    case 6: if (idx < 16384) wb[327680 + idx] = f2b(sW[idx]);           break;
    case 7: if (idx < 16384) wb[344064 + idx] = f2b(oW[idx]);           break;
    case 8: if (idx < 12288) wb[360448 + idx] = f2b(pW[idx]);           break;
    case 9:                                                                   // xT[b][c][l] = x[b][l][c]
        for (int i = idx; i < 86016; i += 65536){
            int bc = i >> 7, l = i & 127;
            int b = bc / 21, c = bc % 21;
            xT[i] = x[(b * 128 + l) * 21 + c];
        }
        break;
    }
}

// ---------- fused head: embed + layernorm -> c0 = xn@vW^T+vb -> X0 = c0@Wx0^T+b0 ----------
// grid 336, block 64 (ONE wave, 16 rows, zero barriers). xn & c0 live only in LDS.
__global__ __launch_bounds__(64) void head_k(
    const float* __restrict__ xT, const float* __restrict__ eW,
    const float* __restrict__ eb, const float* __restrict__ lng,
    const float* __restrict__ lnb, const ushort_t* __restrict__ vWb,
    const float* __restrict__ vb, const ushort_t* __restrict__ wx0b,
    const float* __restrict__ lb, float* __restrict__ xnF, float* __restrict__ X0F)
{
    __shared__ ushort_t xnL[2048];   // 16x128 bf16, swizzled
    __shared__ ushort_t c0L[2048];

    const int lane = threadIdx.x;
    const int rowbase = blockIdx.x * 16;
    const int e0 = lane, e1 = lane + 64;

    float w0[16], w1[16];
#pragma unroll
    for (int p = 0; p < 16; ++p){ w0[p] = eW[e0 * 16 + p]; w1[p] = eW[e1 * 16 + p]; }
    const float bi0 = eb[e0], bi1 = eb[e1];
    const float ga0 = lng[e0], ga1 = lng[e1];
    const float be0 = lnb[e0], be1 = lnb[e1];

    for (int i = 0; i < 16; ++i){
        const int row = rowbase + i;
        const int bc = row >> 3, n = row & 7;
        const float* xp = xT + bc * 128 + n * 16;   // contiguous, wave-uniform
        float v0 = bi0, v1 = bi1;
#pragma unroll
        for (int p = 0; p < 16; ++p){
            float pv = xp[p];
            v0 += w0[p] * pv; v1 += w1[p] * pv;
        }
        float s = v0 + v1, sq = v0 * v0 + v1 * v1;
#pragma unroll
        for (int m = 32; m >= 1; m >>= 1){
            s  += __shfl_xor(s,  m);
            sq += __shfl_xor(sq, m);
        }
        float mean = s * (1.f / 128.f);
        float var  = sq * (1.f / 128.f) - mean * mean;
        float r    = rsqrtf(var + 1e-5f);
        float y0 = (v0 - mean) * r * ga0 + be0;
        float y1 = (v1 - mean) * r * ga1 + be1;
        xnF[row * 128 + e0] = y0;
        xnF[row * 128 + e1] = y1;
        const int sz = (i & 7) << 3;
        xnL[i * 128 + (e0 ^ sz)] = f2b(y0);
        xnL[i * 128 + (e1 ^ sz)] = f2b(y1);
    }

    const int r0 = lane & 15, g = lane >> 4, sw = r0 & 7;
    // c0 = xn @ vW^T + vb  -> c0L
    {
        bf16x8 a[4];
#pragma unroll
        for (int kt = 0; kt < 4; ++kt)
            a[kt] = *(const bf16x8*)(&xnL[r0 * 128 + ((kt * 32 + g * 8) ^ (sw << 3))]);
#pragma unroll
        for (int nt = 0; nt < 8; ++nt){
            const int col = nt * 16 + r0;
            float bv = vb[col];
            f32x4 acc = {bv, bv, bv, bv};
#pragma unroll
            for (int kt = 0; kt < 4; ++kt)
                acc = __builtin_amdgcn_mfma_f32_16x16x32_bf16(
                        a[kt], *(const bf16x8*)(vWb + col * 128 + kt * 32 + g * 8), acc, 0, 0, 0);
#pragma unroll
            for (int q = 0; q < 4; ++q){
                int rr = g * 4 + q;
                c0L[rr * 128 + (col ^ ((rr & 7) << 3))] = f2b(acc[q]);
            }
        }
    }
    // X0 = c0 @ Wx0^T + b0  -> X0F (f32, [row5376][512])
    {
        bf16x8 a[4];
#pragma unroll
        for (int kt = 0; kt < 4; ++kt)
            a[kt] = *(const bf16x8*)(&c0L[r0 * 128 + ((kt * 32 + g * 8) ^ (sw << 3))]);
        for (int nt = 0; nt < 32; ++nt){
            const int col = nt * 16 + r0;
            float bv = lb[col];
            f32x4 acc = {bv, bv, bv, bv};
#pragma unroll
            for (int kt = 0; kt < 4; ++kt)
                acc = __builtin_amdgcn_mfma_f32_16x16x32_bf16(
                        a[kt], *(const bf16x8*)(wx0b + col * 128 + kt * 32 + g * 8), acc, 0, 0, 0);
#pragma unroll
            for (int q = 0; q < 4; ++q)
                X0F[(rowbase + g * 4 + q) * 512 + col] = acc[q];
        }
    }
}

// ---------- fused 2-layer LSTM, layer-pipelined, ALL weights in registers ----------
// grid 42, block 256 (4 waves, 1 wave/SIMD -> 512-reg budget). 16 batch rows/block.
// Wave w owns hidden cols w*32..w*32+31 (8 gate col-tiles). Wh0+Wx1+Wh1 = 96
// fragments = 384 regs register/AGPR-resident; LDS only holds h-state (16 KB).
// Phase ph: L0(t=ph) and L1(t=ph-1) share the a0/ah fragments in one kt loop.
__global__ __launch_bounds__(256, 1) void lstm_f4(
    const float* __restrict__ X0, const ushort_t* __restrict__ Wh0,
    const ushort_t* __restrict__ Wx1, const ushort_t* __restrict__ Wh1,
    const float* __restrict__ lb, ushort_t* __restrict__ outB)
{
    __shared__ ushort_t hbuf[8192];   // [h0 p0][h0 p1][h1 p0][h1 p1] x 2048

    const int tid = threadIdx.x;
    const int w = tid >> 6, lane = tid & 63;
    const int r0 = lane & 15, g = lane >> 4;
    const int sw = r0 & 7;
    const int bcb = blockIdx.x * 16;
    const float K1 = 1.44269504f, K2 = 2.88539008f;

    for (int i = tid; i < 8192; i += 256) hbuf[i] = 0;

    // 96 weight fragments; t8 = g4*2+ct, col = g4*128 + w*32 + ct*16 + r0
    bf16x8 wh0[8][4], wh1[8][4], wx1[8][4];
#pragma unroll
    for (int t8 = 0; t8 < 8; ++t8){
        const int col = (t8 >> 1) * 128 + w * 32 + (t8 & 1) * 16 + r0;
#pragma unroll
        for (int kt = 0; kt < 4; ++kt){
            wh0[t8][kt] = *(const bf16x8*)(Wh0 + col * 128 + kt * 32 + g * 8);
            wh1[t8][kt] = *(const bf16x8*)(Wh1 + col * 128 + kt * 32 + g * 8);
            wx1[t8][kt] = *(const bf16x8*)(Wx1 + col * 128 + kt * 32 + g * 8);
        }
    }
    float b1v[8];
#pragma unroll
    for (int t8 = 0; t8 < 8; ++t8)
        b1v[t8] = lb[512 + (t8 >> 1) * 128 + w * 32 + (t8 & 1) * 16 + r0];

    // hoisted h write addresses: wq = ct*4+q
    char* wrq[8];
#pragma unroll
    for (int wq = 0; wq < 8; ++wq){
        const int q = wq & 3, ct = wq >> 2;
        const int row = g * 4 + q;
        const int col = w * 32 + ct * 16 + r0;
        wrq[wq] = (char*)hbuf + row * 256 + ((col ^ ((row & 7) << 3)) << 1);
    }
    // X0 running pointers (per q); per-t8 offsets are compile-time immediates
    const char* xp[4];
#pragma unroll
    for (int q = 0; q < 4; ++q)
        xp[q] = (const char*)(X0 + (bcb + g * 4 + q) * 4096 + w * 32 + r0);

    float c0[8], c1[8];
#pragma unroll
    for (int i = 0; i < 8; ++i){ c0[i] = 0.f; c1[i] = 0.f; }

    // acc preloaded with X0(t=0); accB is the L1 accumulator
    f32x4 acc[8], accB[8];
#pragma unroll
    for (int t8 = 0; t8 < 8; ++t8)
#pragma unroll
        for (int q = 0; q < 4; ++q)
            acc[t8][q] = *(const float*)(xp[q] + (((t8 >> 1) * 128 + (t8 & 1) * 16) << 2));
#pragma unroll
    for (int q = 0; q < 4; ++q) xp[q] += 2048;
    int tnn = 1;

    __syncthreads();

#pragma unroll 1
    for (int tt = 0; tt < 32; ++tt){
#pragma unroll
        for (int pp = 0; pp < 2; ++pp){
            const int ph = tt * 2 + pp;
            const int RDO = (pp ^ 1) * 4096;     // buffers written in phase ph-1
            const int WRO = pp * 4096;

            if (ph > 0){
#pragma unroll
                for (int t8 = 0; t8 < 8; ++t8){
                    f32x4 tmp = {b1v[t8], b1v[t8], b1v[t8], b1v[t8]};
                    accB[t8] = tmp;
                }
            }

            // shared kt loop: a0/ah read ONCE feed L0 (wh0) and L1 (wx1+wh1)
#pragma unroll
            for (int kt = 0; kt < 4; ++kt){
                const char* ab = (const char*)hbuf + r0 * 256
                               + (((kt * 32 + g * 8) ^ (sw << 3)) << 1);
                bf16x8 a0 = *(const bf16x8*)(ab + RDO);
                bf16x8 ah = *(const bf16x8*)(ab + 8192 + RDO);
#pragma unroll
                for (int t8 = 0; t8 < 8; ++t8)
                    acc[t8] = __builtin_amdgcn_mfma_f32_16x16x32_bf16(a0, wh0[t8][kt], acc[t8], 0, 0, 0);
                if (ph > 0){
#pragma unroll
                    for (int t8 = 0; t8 < 8; ++t8){
                        accB[t8] = __builtin_amdgcn_mfma_f32_16x16x32_bf16(a0, wx1[t8][kt], accB[t8], 0, 0, 0);
                        accB[t8] = __builtin_amdgcn_mfma_f32_16x16x32_bf16(ah, wh1[t8][kt], accB[t8], 0, 0, 0);
                    }
                }
            }

            // ---- EW layer 0 -> h0[pp] ----
            if (ph < 64){
#pragma unroll
                for (int ct = 0; ct < 2; ++ct)
#pragma unroll
                for (int q = 0; q < 4; ++q){
                    float iv = acc[ct][q], fv = acc[2 + ct][q];
                    float gv = acc[4 + ct][q], ov = acc[6 + ct][q];
                    float af = 1.f + __builtin_amdgcn_exp2f(-K1 * fv);
                    float ai = 1.f + __builtin_amdgcn_exp2f(-K1 * iv);
                    float bg = 1.f + __builtin_amdgcn_exp2f( K2 * gv);
                    float cn = c0[ct * 4 + q] * __builtin_amdgcn_rcpf(af)
                             + (bg - 2.f) * __builtin_amdgcn_rcpf(ai * bg);
                    c0[ct * 4 + q] = cn;
                    float ao = 1.f + __builtin_amdgcn_exp2f(-K1 * ov);
                    float bc = 1.f + __builtin_amdgcn_exp2f( K2 * cn);
                    float hv = (bc - 2.f) * __builtin_amdgcn_rcpf(ao * bc);
                    *(ushort_t*)(wrq[ct * 4 + q] + WRO) = f2b(hv);
                }
                // X0 prefetch for t = ph+1 into (now dead) acc
                if (ph < 63){
#pragma unroll
                    for (int t8 = 0; t8 < 8; ++t8)
#pragma unroll
                        for (int q = 0; q < 4; ++q)
                            acc[t8][q] = *(const float*)(xp[q] + (((t8 >> 1) * 128 + (t8 & 1) * 16) << 2));
                    long d = (tnn == 7) ? -14336L : 2048L;
                    tnn = (tnn == 7) ? 0 : tnn + 1;
#pragma unroll
                    for (int q = 0; q < 4; ++q) xp[q] += d;
                }
            }

            // ---- EW layer 1 -> h1[pp] (+ output for t >= 56) ----
            if (ph > 0){
#pragma unroll
                for (int ct = 0; ct < 2; ++ct)
#pragma unroll
                for (int q = 0; q < 4; ++q){
                    float iv = accB[ct][q], fv = accB[2 + ct][q];
                    float gv = accB[4 + ct][q], ov = accB[6 + ct][q];
                    float af = 1.f + __builtin_amdgcn_exp2f(-K1 * fv);
                    float ai = 1.f + __builtin_amdgcn_exp2f(-K1 * iv);
                    float bg = 1.f + __builtin_amdgcn_exp2f( K2 * gv);
                    float cn = c1[ct * 4 + q] * __builtin_amdgcn_rcpf(af)
                             + (bg - 2.f) * __builtin_amdgcn_rcpf(ai * bg);
                    c1[ct * 4 + q] = cn;
                    float ao = 1.f + __builtin_amdgcn_exp2f(-K1 * ov);
                    float bc = 1.f + __builtin_amdgcn_exp2f( K2 * cn);
                    float hv = (bc - 2.f) * __builtin_amdgcn_rcpf(ao * bc);
                    *(ushort_t*)(wrq[ct * 4 + q] + 8192 + WRO) = f2b(hv);
                    if (ph >= 57){
                        int row = g * 4 + q;
                        outB[((bcb + row) * 8 + ((ph - 1) & 7)) * 128 + w * 32 + ct * 16 + r0] = f2b(hv);
                    }
                }
            }
            __syncthreads();
        }
    }

    // ---- epilogue phase ph = 64: L1 only (t = 63), reads buffers of ph=63 ----
    {
        f32x4 acc2[8];
#pragma unroll
        for (int t8 = 0; t8 < 8; ++t8){
            f32x4 tmp = {b1v[t8], b1v[t8], b1v[t8], b1v[t8]};
            acc2[t8] = tmp;
        }
#pragma unroll
        for (int kt = 0; kt < 4; ++kt){
            const char* ab = (const char*)hbuf + r0 * 256
                           + (((kt * 32 + g * 8) ^ (sw << 3)) << 1);
            bf16x8 a0 = *(const bf16x8*)(ab + 4096);
            bf16x8 ah = *(const bf16x8*)(ab + 8192 + 4096);
#pragma unroll
            for (int t8 = 0; t8 < 8; ++t8){
                acc2[t8] = __builtin_amdgcn_mfma_f32_16x16x32_bf16(a0, wx1[t8][kt], acc2[t8], 0, 0, 0);
                acc2[t8] = __builtin_amdgcn_mfma_f32_16x16x32_bf16(ah, wh1[t8][kt], acc2[t8], 0, 0, 0);
            }
        }
#pragma unroll
        for (int ct = 0; ct < 2; ++ct)
#pragma unroll
        for (int q = 0; q < 4; ++q){
            float iv = acc2[ct][q], fv = acc2[2 + ct][q];
            float gv = acc2[4 + ct][q], ov = acc2[6 + ct][q];
            float af = 1.f + __builtin_amdgcn_exp2f(-K1 * fv);
            float ai = 1.f + __builtin_amdgcn_exp2f(-K1 * iv);
            float bg = 1.f + __builtin_amdgcn_exp2f( K2 * gv);
            float cn = c1[ct * 4 + q] * __builtin_amdgcn_rcpf(af)
                     + (bg - 2.f) * __builtin_amdgcn_rcpf(ai * bg);
            float ao = 1.f + __builtin_amdgcn_exp2f(-K1 * ov);
            float bc = 1.f + __builtin_amdgcn_exp2f( K2 * cn);
            float hv = (bc - 2.f) * __builtin_amdgcn_rcpf(ao * bc);
            int row = g * 4 + q;
            outB[((bcb + row) * 8 + 7) * 128 + w * 32 + ct * 16 + r0] = f2b(hv);
        }
    }
}

// ---------- fused tail: conv1d(SAME,K=3) -> ssm -> outp(+resid xn) -> proj ----------
__global__ __launch_bounds__(256) void tail_k(
    const ushort_t* __restrict__ ls, const ushort_t* __restrict__ cWk,
    const float* __restrict__ cbias, const ushort_t* __restrict__ sW,
    const float* __restrict__ sbias, const ushort_t* __restrict__ oW,
    const float* __restrict__ obias, const float* __restrict__ xnF,
    const ushort_t* __restrict__ pW, const float* __restrict__ pbias,
    float* __restrict__ out)
{
    __shared__ ushort_t bufA[8192];
    __shared__ ushort_t bufB[8192];
    const int lane = threadIdx.x & 63, wave = threadIdx.x >> 6;
    const int r0 = lane & 15, g = lane >> 4;
    const int rowbase = blockIdx.x * 64;
    const int lr0 = wave * 16;

    // ---- conv ----
    {
        const int n = r0 & 7;
        bf16x8 a[3][4];
#pragma unroll
        for (int k = 0; k < 3; ++k){
            bool valid = (n + k >= 1) && (n + k <= 8);
            const ushort_t* ap = ls + (rowbase + lr0 + r0 + k - 1) * 128 + g * 8;
#pragma unroll
            for (int kt = 0; kt < 4; ++kt){
                bf16x8 z = {0,0,0,0,0,0,0,0};
                a[k][kt] = valid ? *(const bf16x8*)(ap + kt * 32) : z;
            }
        }
#pragma unroll
        for (int nt = 0; nt < 8; ++nt){
            const int col = nt * 16 + r0;
            float bv = cbias[col];
            f32x4 acc = {bv, bv, bv, bv};
#pragma unroll
            for (int k = 0; k < 3; ++k)
#pragma unroll
                for (int kt = 0; kt < 4; ++kt)
                    acc = __builtin_amdgcn_mfma_f32_16x16x32_bf16(
                            a[k][kt], *(const bf16x8*)(cWk + k * 16384 + col * 128 + kt * 32 + g * 8),
                            acc, 0, 0, 0);
#pragma unroll
            for (int q = 0; q < 4; ++q){
                int row = lr0 + g * 4 + q;
                bufA[row * 128 + (col ^ ((row & 7) << 3))] = f2b(acc[q]);
            }
        }
    }
    __syncthreads();
    // ---- ssm: bufA -> bufB ----
    {
        bf16x8 a[4];
#pragma unroll
        for (int kt = 0; kt < 4; ++kt)
            a[kt] = *(const bf16x8*)(&bufA[(lr0 + r0) * 128 + ((kt * 32 + g * 8) ^ ((r0 & 7) << 3))]);
#pragma unroll
        for (int nt = 0; nt < 8; ++nt){
            const int col = nt * 16 + r0;
            float bv = sbias[col];
            f32x4 acc = {bv, bv, bv, bv};
#pragma unroll
            for (int kt = 0; kt < 4; ++kt)
                acc = __builtin_amdgcn_mfma_f32_16x16x32_bf16(
                        a[kt], *(const bf16x8*)(sW + col * 128 + kt * 32 + g * 8), acc, 0, 0, 0);
#pragma unroll
            for (int q = 0; q < 4; ++q){
                int row = lr0 + g * 4 + q;
                bufB[row * 128 + (col ^ ((row & 7) << 3))] = f2b(acc[q]);
            }
        }
    }
    __syncthreads();
    // ---- outp + resid: bufB -> bufA ----
    {
        bf16x8 a[4];
#pragma unroll
        for (int kt = 0; kt < 4; ++kt)
            a[kt] = *(const bf16x8*)(&bufB[(lr0 + r0) * 128 + ((kt * 32 + g * 8) ^ ((r0 & 7) << 3))]);
#pragma unroll
        for (int nt = 0; nt < 8; ++nt){
            const int col = nt * 16 + r0;
            float bv = obias[col];
            f32x4 acc = {bv, bv, bv, bv};
#pragma unroll
            for (int kt = 0; kt < 4; ++kt)
                acc = __builtin_amdgcn_mfma_f32_16x16x32_bf16(
                        a[kt], *(const bf16x8*)(oW + col * 128 + kt * 32 + g * 8), acc, 0, 0, 0);
#pragma unroll
            for (int q = 0; q < 4; ++q){
                int row = lr0 + g * 4 + q;
                float v = acc[q] + xnF[(rowbase + row) * 128 + col];
                bufA[row * 128 + (col ^ ((row & 7) << 3))] = f2b(v);
            }
        }
    }
    __syncthreads();
    // ---- proj: bufA -> out (96 cols, f32) ----
    {
        bf16x8 a[4];
#pragma unroll
        for (int kt = 0; kt < 4; ++kt)
            a[kt] = *(const bf16x8*)(&bufA[(lr0 + r0) * 128 + ((kt * 32 + g * 8) ^ ((r0 & 7) << 3))]);
#pragma unroll
        for (int nt = 0; nt < 6; ++nt){
            const int col = nt * 16 + r0;
            float bv = pbias[col];
            f32x4 acc = {bv, bv, bv, bv};
#pragma unroll
            for (int kt = 0; kt < 4; ++kt)
                acc = __builtin_amdgcn_mfma_f32_16x16x32_bf16(
                        a[kt], *(const bf16x8*)(pW + col * 128 + kt * 32 + g * 8), acc, 0, 0, 0);
#pragma unroll
            for (int q = 0; q < 4; ++q)
                out[(rowbase + lr0 + g * 4 + q) * 96 + col] = acc[q];
        }
    }
}

// ---------- launch ----------
extern "C" void kernel_launch(void* const* d_in, const int* in_sizes, int n_in,
                              void* d_out, int out_size, void* d_ws, size_t ws_size,
                              hipStream_t stream)
{
    const float* x   = (const float*)d_in[0];
    const float* eW  = (const float*)d_in[1];
    const float* eb  = (const float*)d_in[2];
    const float* lng = (const float*)d_in[3];
    const float* lnb = (const float*)d_in[4];
    const float* vW  = (const float*)d_in[9];
    const float* vb  = (const float*)d_in[10];
    const float* Wx  = (const float*)d_in[11];
    const float* Wh  = (const float*)d_in[12];
    const float* lb  = (const float*)d_in[13];
    const float* cW  = (const float*)d_in[14];
    const float* cb_ = (const float*)d_in[15];
    const float* sW  = (const float*)d_in[16];
    const float* sb  = (const float*)d_in[17];
    const float* oW  = (const float*)d_in[18];
    const float* ob  = (const float*)d_in[19];
    const float* pW  = (const float*)d_in[20];
    const float* pb  = (const float*)d_in[21];

    char* ws = (char*)d_ws;
    float*    xnF = (float*)   (ws + 0);          // 5376x128 f32   (2.75 MB)
    float*    X0F = (float*)   (ws + 5505024);    // 5376x512 f32   (11 MB)
    ushort_t* lsB = (ushort_t*)(ws + 16515072);   // lstm out bf16  (1.38 MB)
    ushort_t* wb  = (ushort_t*)(ws + 17891328);   // bf16 weights   (0.75 MB)
    float*    xT  = (float*)   (ws + 18874368);   // x transposed [b][c][l] (344 KB)

    prep_k<<<dim3(256, 10), 256, 0, stream>>>(vW, Wx, Wh, cW, sW, oW, pW, x, wb, xT);
    // fused embed+LN -> c0 -> X0 (single-wave blocks; contiguous xT patch reads)
    head_k<<<336, 64, 0, stream>>>(xT, eW, eb, lng, lnb, wb + 0, vb, wb + 16384, lb,
                                   xnF, X0F);
    // fused layer-pipelined 2-layer recurrence, 4 waves/block, all-register weights
    lstm_f4<<<42, 256, 0, stream>>>(X0F, wb + 81920, wb + 147456, wb + 212992,
                                    lb, lsB);
    tail_k<<<84, 256, 0, stream>>>(lsB, wb + 278528, cb_, wb + 327680, sb,
                                   wb + 344064, ob, xnF, wb + 360448, pb, (float*)d_out);
}

// Round 13
// 201.642 us; speedup vs baseline: 2.4121x; 2.4121x over previous
//
#include <hip/hip_runtime.h>

typedef unsigned short ushort_t;
typedef unsigned int uint_t;

using bf16x8 = __attribute__((ext_vector_type(8))) short;
using f32x4  = __attribute__((ext_vector_type(4))) float;

// ---------- helpers ----------
__device__ __forceinline__ ushort_t f2b(float f){
    union { float f; uint_t u; } v; v.f = f;
    uint_t u = v.u;
    uint_t r = (u + 0x7FFFu + ((u >> 16) & 1u)) >> 16;   // RNE
    return (ushort_t)r;
}

// ---------- weight prep: f32 -> bf16 (+ conv restride) + x transpose ----------
__global__ void prep_k(const float* __restrict__ vW, const float* __restrict__ Wx,
                       const float* __restrict__ Wh, const float* __restrict__ cW,
                       const float* __restrict__ sW, const float* __restrict__ oW,
                       const float* __restrict__ pW, const float* __restrict__ x,
                       ushort_t* __restrict__ wb, float* __restrict__ xT)
{
    int idx = blockIdx.x * 256 + threadIdx.x;
    switch (blockIdx.y){
    case 0: if (idx < 16384) wb[idx]          = f2b(vW[idx]);           break;
    case 1: if (idx < 65536) wb[16384  + idx] = f2b(Wx[idx]);           break; // Wx0
    case 2: if (idx < 65536) wb[81920  + idx] = f2b(Wh[idx]);           break; // Wh0
    case 3: if (idx < 65536) wb[147456 + idx] = f2b(Wx[65536 + idx]);   break; // Wx1
    case 4: if (idx < 65536) wb[212992 + idx] = f2b(Wh[65536 + idx]);   break; // Wh1
    case 5: if (idx < 49152){                                                  // conv [k][o][i]
                int k = idx >> 14; int oi = idx & 16383;
                wb[278528 + idx] = f2b(cW[oi * 3 + k]);
            } break;
    case 6: if (idx < 16384) wb[327680 + idx] = f2b(sW[idx]);           break;
    case 7: if (idx < 16384) wb[344064 + idx] = f2b(oW[idx]);           break;
    case 8: if (idx < 12288) wb[360448 + idx] = f2b(pW[idx]);           break;
    case 9:                                                                   // xT[b][c][l] = x[b][l][c]
        for (int i = idx; i < 86016; i += 65536){
            int bc = i >> 7, l = i & 127;
            int b = bc / 21, c = bc % 21;
            xT[i] = x[(b * 128 + l) * 21 + c];
        }
        break;
    }
}

// ---------- fused head: embed + layernorm -> c0 = xn@vW^T+vb -> X0 = c0@Wx0^T+b0 ----------
// grid 336, block 256 (4 waves). LN rows 4/wave; c0 tiles 2/wave; X0 tiles 8/wave.
// xn & c0 live in shared LDS (swizzled); 2 barriers.
__global__ __launch_bounds__(256) void head_k(
    const float* __restrict__ xT, const float* __restrict__ eW,
    const float* __restrict__ eb, const float* __restrict__ lng,
    const float* __restrict__ lnb, const ushort_t* __restrict__ vWb,
    const float* __restrict__ vb, const ushort_t* __restrict__ wx0b,
    const float* __restrict__ lb, float* __restrict__ xnF, float* __restrict__ X0F)
{
    __shared__ ushort_t xnL[2048];   // 16x128 bf16, swizzled
    __shared__ ushort_t c0L[2048];

    const int tid = threadIdx.x;
    const int wv = tid >> 6, lane = tid & 63;
    const int rowbase = blockIdx.x * 16;
    const int e0 = lane, e1 = lane + 64;

    float w0[16], w1[16];
#pragma unroll
    for (int p = 0; p < 16; ++p){ w0[p] = eW[e0 * 16 + p]; w1[p] = eW[e1 * 16 + p]; }
    const float bi0 = eb[e0], bi1 = eb[e1];
    const float ga0 = lng[e0], ga1 = lng[e1];
    const float be0 = lnb[e0], be1 = lnb[e1];

    // LN: 4 rows per wave
    for (int i = wv; i < 16; i += 4){
        const int row = rowbase + i;
        const int bc = row >> 3, n = row & 7;
        const float* xp = xT + bc * 128 + n * 16;   // contiguous, wave-uniform
        float v0 = bi0, v1 = bi1;
#pragma unroll
        for (int p = 0; p < 16; ++p){
            float pv = xp[p];
            v0 += w0[p] * pv; v1 += w1[p] * pv;
        }
        float s = v0 + v1, sq = v0 * v0 + v1 * v1;
#pragma unroll
        for (int m = 32; m >= 1; m >>= 1){
            s  += __shfl_xor(s,  m);
            sq += __shfl_xor(sq, m);
        }
        float mean = s * (1.f / 128.f);
        float var  = sq * (1.f / 128.f) - mean * mean;
        float r    = rsqrtf(var + 1e-5f);
        float y0 = (v0 - mean) * r * ga0 + be0;
        float y1 = (v1 - mean) * r * ga1 + be1;
        xnF[row * 128 + e0] = y0;
        xnF[row * 128 + e1] = y1;
        const int sz = (i & 7) << 3;
        xnL[i * 128 + (e0 ^ sz)] = f2b(y0);
        xnL[i * 128 + (e1 ^ sz)] = f2b(y1);
    }
    __syncthreads();

    const int r0 = lane & 15, g = lane >> 4, sw = r0 & 7;
    bf16x8 a[4];
#pragma unroll
    for (int kt = 0; kt < 4; ++kt)
        a[kt] = *(const bf16x8*)(&xnL[r0 * 128 + ((kt * 32 + g * 8) ^ (sw << 3))]);

    // c0 = xn @ vW^T + vb : tiles nt = wv*2, wv*2+1
#pragma unroll
    for (int j = 0; j < 2; ++j){
        const int nt = wv * 2 + j;
        const int col = nt * 16 + r0;
        float bv = vb[col];
        f32x4 acc = {bv, bv, bv, bv};
#pragma unroll
        for (int kt = 0; kt < 4; ++kt)
            acc = __builtin_amdgcn_mfma_f32_16x16x32_bf16(
                    a[kt], *(const bf16x8*)(vWb + col * 128 + kt * 32 + g * 8), acc, 0, 0, 0);
#pragma unroll
        for (int q = 0; q < 4; ++q){
            int rr = g * 4 + q;
            c0L[rr * 128 + (col ^ ((rr & 7) << 3))] = f2b(acc[q]);
        }
    }
    __syncthreads();

#pragma unroll
    for (int kt = 0; kt < 4; ++kt)
        a[kt] = *(const bf16x8*)(&c0L[r0 * 128 + ((kt * 32 + g * 8) ^ (sw << 3))]);

    // X0 = c0 @ Wx0^T + b0 : tiles nt = wv*8 .. wv*8+7
#pragma unroll
    for (int j = 0; j < 8; ++j){
        const int nt = wv * 8 + j;
        const int col = nt * 16 + r0;
        float bv = lb[col];
        f32x4 acc = {bv, bv, bv, bv};
#pragma unroll
        for (int kt = 0; kt < 4; ++kt)
            acc = __builtin_amdgcn_mfma_f32_16x16x32_bf16(
                    a[kt], *(const bf16x8*)(wx0b + col * 128 + kt * 32 + g * 8), acc, 0, 0, 0);
#pragma unroll
        for (int q = 0; q < 4; ++q)
            X0F[(rowbase + g * 4 + q) * 512 + col] = acc[q];
    }
}

// ---------- fused 2-layer LSTM, layer-pipelined (65 phases) ----------
// grid 42, block 512 (8 waves, 2/SIMD). 16 batch rows/block.
// Phase ph: L0(t=ph) [ph<64] CONCURRENT WITH L1(t=ph-1) [ph>0].
// Wh0+Wh1 register/AGPR-resident (128); Wx1 in 128KB LDS (swizzled, addresses
// hoisted). One barrier/phase. X0 prefetch into dead acc via running pointers.
__global__ __launch_bounds__(512, 2) void lstm_f2(
    const float* __restrict__ X0, const ushort_t* __restrict__ Wh0,
    const ushort_t* __restrict__ Wx1, const ushort_t* __restrict__ Wh1,
    const float* __restrict__ lb, ushort_t* __restrict__ outB)
{
    extern __shared__ ushort_t smem[];
    ushort_t* hbuf = smem;
    ushort_t* wxs  = smem + 8192;

    const int tid = threadIdx.x;
    const int wid = tid >> 6, lane = tid & 63;
    const int r0 = lane & 15, g = lane >> 4;
    const int sw = r0 & 7;
    const int bcb = blockIdx.x * 16;
    const float K1 = 1.44269504f, K2 = 2.88539008f;

    for (int i = tid; i < 8192; i += 512) hbuf[i] = 0;
    for (int idx = tid; idx < 8192; idx += 512){
        int col = idx >> 4, c = idx & 15;
        *(bf16x8*)(wxs + col * 128 + ((c ^ (col & 7)) << 3)) =
            *(const bf16x8*)(Wx1 + col * 128 + c * 8);
    }

    bf16x8 wh0[4][4], wh1[4][4];
#pragma unroll
    for (int t4 = 0; t4 < 4; ++t4){
        const int cb = t4 * 128 + wid * 16;
#pragma unroll
        for (int kt = 0; kt < 4; ++kt){
            wh0[t4][kt] = *(const bf16x8*)(Wh0 + (cb + r0) * 128 + kt * 32 + g * 8);
            wh1[t4][kt] = *(const bf16x8*)(Wh1 + (cb + r0) * 128 + kt * 32 + g * 8);
        }
    }
    float b1v[4];
#pragma unroll
    for (int t4 = 0; t4 < 4; ++t4) b1v[t4] = lb[512 + t4 * 128 + wid * 16 + r0];

    const char* adr[4];
#pragma unroll
    for (int kt = 0; kt < 4; ++kt)
        adr[kt] = (const char*)hbuf + r0 * 256 + (((kt * 32 + g * 8) ^ (sw << 3)) << 1);
    char* wrq[4];
#pragma unroll
    for (int q = 0; q < 4; ++q){
        int row = g * 4 + q;
        wrq[q] = (char*)hbuf + row * 256 + (((wid * 16 + r0) ^ ((row & 7) << 3)) << 1);
    }
    const char* wxp[4][2];
    {
        const int e = (sw >> 2) * 64;
#pragma unroll
        for (int t4 = 0; t4 < 4; ++t4){
            const char* base = (const char*)wxs
                + (t4 * 128 + wid * 16 + r0) * 256 + ((g ^ (sw & 3)) * 16);
            wxp[t4][0] = base + e;
            wxp[t4][1] = base + (64 - e);
        }
    }
    const char* xp[4];
#pragma unroll
    for (int q = 0; q < 4; ++q)
        xp[q] = (const char*)(X0 + (bcb + g * 4 + q) * 4096 + wid * 16 + r0) + 2048;
    int tnn = 1;

    float c0[4] = {0,0,0,0}, c1[4] = {0,0,0,0};

    f32x4 acc[4];
#pragma unroll
    for (int t4 = 0; t4 < 4; ++t4)
#pragma unroll
        for (int q = 0; q < 4; ++q)
            acc[t4][q] = *(const float*)(xp[q] - 2048 + t4 * 512);

    __syncthreads();

#pragma unroll 1
    for (int tt = 0; tt < 32; ++tt){
#pragma unroll
        for (int pp = 0; pp < 2; ++pp){
            const int ph = tt * 2 + pp;
            const int RDO = (pp ^ 1) * 4096;
            const int WRO = pp * 4096;

            bf16x8 a0[4], ah[4];
#pragma unroll
            for (int kt = 0; kt < 4; ++kt){
                a0[kt] = *(const bf16x8*)(adr[kt] + RDO);
                ah[kt] = *(const bf16x8*)(adr[kt] + 8192 + RDO);
            }

#pragma unroll
            for (int kt = 0; kt < 4; ++kt)
#pragma unroll
                for (int t4 = 0; t4 < 4; ++t4)
                    acc[t4] = __builtin_amdgcn_mfma_f32_16x16x32_bf16(a0[kt], wh0[t4][kt], acc[t4], 0, 0, 0);

#pragma unroll
            for (int q = 0; q < 4; ++q){
                float iv = acc[0][q], fv = acc[1][q], gv = acc[2][q], ov = acc[3][q];
                float af = 1.f + __builtin_amdgcn_exp2f(-K1 * fv);
                float ai = 1.f + __builtin_amdgcn_exp2f(-K1 * iv);
                float bg = 1.f + __builtin_amdgcn_exp2f( K2 * gv);
                float cn = c0[q] * __builtin_amdgcn_rcpf(af)
                         + (bg - 2.f) * __builtin_amdgcn_rcpf(ai * bg);
                c0[q] = cn;
                float ao = 1.f + __builtin_amdgcn_exp2f(-K1 * ov);
                float bc = 1.f + __builtin_amdgcn_exp2f( K2 * cn);
                float hv = (bc - 2.f) * __builtin_amdgcn_rcpf(ao * bc);
                *(ushort_t*)(wrq[q] + WRO) = f2b(hv);
            }

            if (ph > 0){
                f32x4 accB[4];
#pragma unroll
                for (int t4 = 0; t4 < 4; ++t4){
                    f32x4 tmp = {b1v[t4], b1v[t4], b1v[t4], b1v[t4]};
                    accB[t4] = tmp;
                }
#pragma unroll
                for (int kt = 0; kt < 4; ++kt)
#pragma unroll
                    for (int t4 = 0; t4 < 4; ++t4){
                        bf16x8 wx = *(const bf16x8*)(wxp[t4][kt & 1] + ((kt >> 1) << 7));
                        accB[t4] = __builtin_amdgcn_mfma_f32_16x16x32_bf16(a0[kt], wx,          accB[t4], 0, 0, 0);
                        accB[t4] = __builtin_amdgcn_mfma_f32_16x16x32_bf16(ah[kt], wh1[t4][kt], accB[t4], 0, 0, 0);
                    }
#pragma unroll
                for (int q = 0; q < 4; ++q){
                    float iv = accB[0][q], fv = accB[1][q], gv = accB[2][q], ov = accB[3][q];
                    float af = 1.f + __builtin_amdgcn_exp2f(-K1 * fv);
                    float ai = 1.f + __builtin_amdgcn_exp2f(-K1 * iv);
                    float bg = 1.f + __builtin_amdgcn_exp2f( K2 * gv);
                    float cn = c1[q] * __builtin_amdgcn_rcpf(af)
                             + (bg - 2.f) * __builtin_amdgcn_rcpf(ai * bg);
                    c1[q] = cn;
                    float ao = 1.f + __builtin_amdgcn_exp2f(-K1 * ov);
                    float bc = 1.f + __builtin_amdgcn_exp2f( K2 * cn);
                    float hv = (bc - 2.f) * __builtin_amdgcn_rcpf(ao * bc);
                    *(ushort_t*)(wrq[q] + 8192 + WRO) = f2b(hv);
                    if (ph >= 57){
                        int row = g * 4 + q;
                        outB[((bcb + row) * 8 + ((ph - 1) & 7)) * 128 + wid * 16 + r0] = f2b(hv);
                    }
                }
            }

            if (ph < 63){
#pragma unroll
                for (int t4 = 0; t4 < 4; ++t4)
#pragma unroll
                    for (int q = 0; q < 4; ++q)
                        acc[t4][q] = *(const float*)(xp[q] + t4 * 512);
                long d = (tnn == 7) ? -14336L : 2048L;
                tnn = (tnn == 7) ? 0 : tnn + 1;
#pragma unroll
                for (int q = 0; q < 4; ++q) xp[q] += d;
            }
            __syncthreads();
        }
    }

    // epilogue phase ph = 64: L1 only (t = 63)
    {
        bf16x8 a0[4], ah[4];
#pragma unroll
        for (int kt = 0; kt < 4; ++kt){
            a0[kt] = *(const bf16x8*)(adr[kt] + 4096);
            ah[kt] = *(const bf16x8*)(adr[kt] + 8192 + 4096);
        }
        f32x4 acc2[4];
#pragma unroll
        for (int t4 = 0; t4 < 4; ++t4){
            f32x4 tmp = {b1v[t4], b1v[t4], b1v[t4], b1v[t4]};
            acc2[t4] = tmp;
        }
#pragma unroll
        for (int kt = 0; kt < 4; ++kt)
#pragma unroll
            for (int t4 = 0; t4 < 4; ++t4){
                bf16x8 wx = *(const bf16x8*)(wxp[t4][kt & 1] + ((kt >> 1) << 7));
                acc2[t4] = __builtin_amdgcn_mfma_f32_16x16x32_bf16(a0[kt], wx,          acc2[t4], 0, 0, 0);
                acc2[t4] = __builtin_amdgcn_mfma_f32_16x16x32_bf16(ah[kt], wh1[t4][kt], acc2[t4], 0, 0, 0);
            }
#pragma unroll
        for (int q = 0; q < 4; ++q){
            float iv = acc2[0][q], fv = acc2[1][q], gv = acc2[2][q], ov = acc2[3][q];
            float af = 1.f + __builtin_amdgcn_exp2f(-K1 * fv);
            float ai = 1.f + __builtin_amdgcn_exp2f(-K1 * iv);
            float bg = 1.f + __builtin_amdgcn_exp2f( K2 * gv);
            float cn = c1[q] * __builtin_amdgcn_rcpf(af)
                     + (bg - 2.f) * __builtin_amdgcn_rcpf(ai * bg);
            float ao = 1.f + __builtin_amdgcn_exp2f(-K1 * ov);
            float bc = 1.f + __builtin_amdgcn_exp2f( K2 * cn);
            float hv = (bc - 2.f) * __builtin_amdgcn_rcpf(ao * bc);
            int row = g * 4 + q;
            outB[((bcb + row) * 8 + 7) * 128 + wid * 16 + r0] = f2b(hv);
        }
    }
}

// ---------- fused tail: conv1d(SAME,K=3) -> ssm -> outp(+resid xn) -> proj ----------
__global__ __launch_bounds__(256) void tail_k(
    const ushort_t* __restrict__ ls, const ushort_t* __restrict__ cWk,
    const float* __restrict__ cbias, const ushort_t* __restrict__ sW,
    const float* __restrict__ sbias, const ushort_t* __restrict__ oW,
    const float* __restrict__ obias, const float* __restrict__ xnF,
    const ushort_t* __restrict__ pW, const float* __restrict__ pbias,
    float* __restrict__ out)
{
    __shared__ ushort_t bufA[8192];
    __shared__ ushort_t bufB[8192];
    const int lane = threadIdx.x & 63, wave = threadIdx.x >> 6;
    const int r0 = lane & 15, g = lane >> 4;
    const int rowbase = blockIdx.x * 64;
    const int lr0 = wave * 16;

    // ---- conv ----
    {
        const int n = r0 & 7;
        bf16x8 a[3][4];
#pragma unroll
        for (int k = 0; k < 3; ++k){
            bool valid = (n + k >= 1) && (n + k <= 8);
            const ushort_t* ap = ls + (rowbase + lr0 + r0 + k - 1) * 128 + g * 8;
#pragma unroll
            for (int kt = 0; kt < 4; ++kt){
                bf16x8 z = {0,0,0,0,0,0,0,0};
                a[k][kt] = valid ? *(const bf16x8*)(ap + kt * 32) : z;
            }
        }
#pragma unroll
        for (int nt = 0; nt < 8; ++nt){
            const int col = nt * 16 + r0;
            float bv = cbias[col];
            f32x4 acc = {bv, bv, bv, bv};
#pragma unroll
            for (int k = 0; k < 3; ++k)
#pragma unroll
                for (int kt = 0; kt < 4; ++kt)
                    acc = __builtin_amdgcn_mfma_f32_16x16x32_bf16(
                            a[k][kt], *(const bf16x8*)(cWk + k * 16384 + col * 128 + kt * 32 + g * 8),
                            acc, 0, 0, 0);
#pragma unroll
            for (int q = 0; q < 4; ++q){
                int row = lr0 + g * 4 + q;
                bufA[row * 128 + (col ^ ((row & 7) << 3))] = f2b(acc[q]);
            }
        }
    }
    __syncthreads();
    // ---- ssm: bufA -> bufB ----
    {
        bf16x8 a[4];
#pragma unroll
        for (int kt = 0; kt < 4; ++kt)
            a[kt] = *(const bf16x8*)(&bufA[(lr0 + r0) * 128 + ((kt * 32 + g * 8) ^ ((r0 & 7) << 3))]);
#pragma unroll
        for (int nt = 0; nt < 8; ++nt){
            const int col = nt * 16 + r0;
            float bv = sbias[col];
            f32x4 acc = {bv, bv, bv, bv};
#pragma unroll
            for (int kt = 0; kt < 4; ++kt)
                acc = __builtin_amdgcn_mfma_f32_16x16x32_bf16(
                        a[kt], *(const bf16x8*)(sW + col * 128 + kt * 32 + g * 8), acc, 0, 0, 0);
#pragma unroll
            for (int q = 0; q < 4; ++q){
                int row = lr0 + g * 4 + q;
                bufB[row * 128 + (col ^ ((row & 7) << 3))] = f2b(acc[q]);
            }
        }
    }
    __syncthreads();
    // ---- outp + resid: bufB -> bufA ----
    {
        bf16x8 a[4];
#pragma unroll
        for (int kt = 0; kt < 4; ++kt)
            a[kt] = *(const bf16x8*)(&bufB[(lr0 + r0) * 128 + ((kt * 32 + g * 8) ^ ((r0 & 7) << 3))]);
#pragma unroll
        for (int nt = 0; nt < 8; ++nt){
            const int col = nt * 16 + r0;
            float bv = obias[col];
            f32x4 acc = {bv, bv, bv, bv};
#pragma unroll
            for (int kt = 0; kt < 4; ++kt)
                acc = __builtin_amdgcn_mfma_f32_16x16x32_bf16(
                        a[kt], *(const bf16x8*)(oW + col * 128 + kt * 32 + g * 8), acc, 0, 0, 0);
#pragma unroll
            for (int q = 0; q < 4; ++q){
                int row = lr0 + g * 4 + q;
                float v = acc[q] + xnF[(rowbase + row) * 128 + col];
                bufA[row * 128 + (col ^ ((row & 7) << 3))] = f2b(v);
            }
        }
    }
    __syncthreads();
    // ---- proj: bufA -> out (96 cols, f32) ----
    {
        bf16x8 a[4];
#pragma unroll
        for (int kt = 0; kt < 4; ++kt)
            a[kt] = *(const bf16x8*)(&bufA[(lr0 + r0) * 128 + ((kt * 32 + g * 8) ^ ((r0 & 7) << 3))]);
#pragma unroll
        for (int nt = 0; nt < 6; ++nt){
            const int col = nt * 16 + r0;
            float bv = pbias[col];
            f32x4 acc = {bv, bv, bv, bv};
#pragma unroll
            for (int kt = 0; kt < 4; ++kt)
                acc = __builtin_amdgcn_mfma_f32_16x16x32_bf16(
                        a[kt], *(const bf16x8*)(pW + col * 128 + kt * 32 + g * 8), acc, 0, 0, 0);
#pragma unroll
            for (int q = 0; q < 4; ++q)
                out[(rowbase + lr0 + g * 4 + q) * 96 + col] = acc[q];
        }
    }
}

// ---------- launch ----------
extern "C" void kernel_launch(void* const* d_in, const int* in_sizes, int n_in,
                              void* d_out, int out_size, void* d_ws, size_t ws_size,
                              hipStream_t stream)
{
    const float* x   = (const float*)d_in[0];
    const float* eW  = (const float*)d_in[1];
    const float* eb  = (const float*)d_in[2];
    const float* lng = (const float*)d_in[3];
    const float* lnb = (const float*)d_in[4];
    const float* vW  = (const float*)d_in[9];
    const float* vb  = (const float*)d_in[10];
    const float* Wx  = (const float*)d_in[11];
    const float* Wh  = (const float*)d_in[12];
    const float* lb  = (const float*)d_in[13];
    const float* cW  = (const float*)d_in[14];
    const float* cb_ = (const float*)d_in[15];
    const float* sW  = (const float*)d_in[16];
    const float* sb  = (const float*)d_in[17];
    const float* oW  = (const float*)d_in[18];
    const float* ob  = (const float*)d_in[19];
    const float* pW  = (const float*)d_in[20];
    const float* pb  = (const float*)d_in[21];

    char* ws = (char*)d_ws;
    float*    xnF = (float*)   (ws + 0);          // 5376x128 f32   (2.75 MB)
    float*    X0F = (float*)   (ws + 5505024);    // 5376x512 f32   (11 MB)
    ushort_t* lsB = (ushort_t*)(ws + 16515072);   // lstm out bf16  (1.38 MB)
    ushort_t* wb  = (ushort_t*)(ws + 17891328);   // bf16 weights   (0.75 MB)
    float*    xT  = (float*)   (ws + 18874368);   // x transposed [b][c][l] (344 KB)

    hipFuncSetAttribute((const void*)lstm_f2,
                        hipFuncAttributeMaxDynamicSharedMemorySize, 147456);

    prep_k<<<dim3(256, 10), 256, 0, stream>>>(vW, Wx, Wh, cW, sW, oW, pW, x, wb, xT);
    // fused embed+LN -> c0 -> X0 (4-wave blocks, work split across waves)
    head_k<<<336, 256, 0, stream>>>(xT, eW, eb, lng, lnb, wb + 0, vb, wb + 16384, lb,
                                    xnF, X0F);
    // fused layer-pipelined 2-layer recurrence (65 phases, one barrier each)
    lstm_f2<<<42, 512, 147456, stream>>>(X0F, wb + 81920, wb + 147456, wb + 212992,
                                         lb, lsB);
    tail_k<<<84, 256, 0, stream>>>(lsB, wb + 278528, cb_, wb + 327680, sb,
                                   wb + 344064, ob, xnF, wb + 360448, pb, (float*)d_out);
}

// Round 14
// 174.114 us; speedup vs baseline: 2.7935x; 1.1581x over previous
//
#include <hip/hip_runtime.h>

typedef unsigned short ushort_t;
typedef unsigned int uint_t;

using bf16x8 = __attribute__((ext_vector_type(8))) short;
using f32x4  = __attribute__((ext_vector_type(4))) float;

// ---------- helpers ----------
__device__ __forceinline__ ushort_t f2b(float f){
    union { float f; uint_t u; } v; v.f = f;
    uint_t u = v.u;
    uint_t r = (u + 0x7FFFu + ((u >> 16) & 1u)) >> 16;   // RNE
    return (ushort_t)r;
}

// ---------- weight prep: f32 -> bf16 (+ conv restride) + x transpose ----------
__global__ void prep_k(const float* __restrict__ vW, const float* __restrict__ Wx,
                       const float* __restrict__ Wh, const float* __restrict__ cW,
                       const float* __restrict__ sW, const float* __restrict__ oW,
                       const float* __restrict__ pW, const float* __restrict__ x,
                       ushort_t* __restrict__ wb, float* __restrict__ xT)
{
    int idx = blockIdx.x * 256 + threadIdx.x;
    switch (blockIdx.y){
    case 0: if (idx < 16384) wb[idx]          = f2b(vW[idx]);           break;
    case 1: if (idx < 65536) wb[16384  + idx] = f2b(Wx[idx]);           break; // Wx0
    case 2: if (idx < 65536) wb[81920  + idx] = f2b(Wh[idx]);           break; // Wh0
    case 3: if (idx < 65536) wb[147456 + idx] = f2b(Wx[65536 + idx]);   break; // Wx1
    case 4: if (idx < 65536) wb[212992 + idx] = f2b(Wh[65536 + idx]);   break; // Wh1
    case 5: if (idx < 49152){                                                  // conv [k][o][i]
                int k = idx >> 14; int oi = idx & 16383;
                wb[278528 + idx] = f2b(cW[oi * 3 + k]);
            } break;
    case 6: if (idx < 16384) wb[327680 + idx] = f2b(sW[idx]);           break;
    case 7: if (idx < 16384) wb[344064 + idx] = f2b(oW[idx]);           break;
    case 8: if (idx < 12288) wb[360448 + idx] = f2b(pW[idx]);           break;
    case 9:                                                                   // xT[b][c][l] = x[b][l][c]
        for (int i = idx; i < 86016; i += 65536){
            int bc = i >> 7, l = i & 127;
            int b = bc / 21, c = bc % 21;
            xT[i] = x[(b * 128 + l) * 21 + c];
        }
        break;
    }
}

// ---------- fused head: embed + layernorm -> c0 = xn@vW^T+vb -> X0 = c0@Wx0^T+b0 ----------
// grid 336, block 256 (4 waves). LN rows 4/wave; c0 tiles 2/wave; X0 tiles 8/wave.
__global__ __launch_bounds__(256) void head_k(
    const float* __restrict__ xT, const float* __restrict__ eW,
    const float* __restrict__ eb, const float* __restrict__ lng,
    const float* __restrict__ lnb, const ushort_t* __restrict__ vWb,
    const float* __restrict__ vb, const ushort_t* __restrict__ wx0b,
    const float* __restrict__ lb, float* __restrict__ xnF, float* __restrict__ X0F)
{
    __shared__ ushort_t xnL[2048];   // 16x128 bf16, swizzled
    __shared__ ushort_t c0L[2048];

    const int tid = threadIdx.x;
    const int wv = tid >> 6, lane = tid & 63;
    const int rowbase = blockIdx.x * 16;
    const int e0 = lane, e1 = lane + 64;

    float w0[16], w1[16];
#pragma unroll
    for (int p = 0; p < 16; ++p){ w0[p] = eW[e0 * 16 + p]; w1[p] = eW[e1 * 16 + p]; }
    const float bi0 = eb[e0], bi1 = eb[e1];
    const float ga0 = lng[e0], ga1 = lng[e1];
    const float be0 = lnb[e0], be1 = lnb[e1];

    // LN: 4 rows per wave
    for (int i = wv; i < 16; i += 4){
        const int row = rowbase + i;
        const int bc = row >> 3, n = row & 7;
        const float* xp = xT + bc * 128 + n * 16;   // contiguous, wave-uniform
        float v0 = bi0, v1 = bi1;
#pragma unroll
        for (int p = 0; p < 16; ++p){
            float pv = xp[p];
            v0 += w0[p] * pv; v1 += w1[p] * pv;
        }
        float s = v0 + v1, sq = v0 * v0 + v1 * v1;
#pragma unroll
        for (int m = 32; m >= 1; m >>= 1){
            s  += __shfl_xor(s,  m);
            sq += __shfl_xor(sq, m);
        }
        float mean = s * (1.f / 128.f);
        float var  = sq * (1.f / 128.f) - mean * mean;
        float r    = rsqrtf(var + 1e-5f);
        float y0 = (v0 - mean) * r * ga0 + be0;
        float y1 = (v1 - mean) * r * ga1 + be1;
        xnF[row * 128 + e0] = y0;
        xnF[row * 128 + e1] = y1;
        const int sz = (i & 7) << 3;
        xnL[i * 128 + (e0 ^ sz)] = f2b(y0);
        xnL[i * 128 + (e1 ^ sz)] = f2b(y1);
    }
    __syncthreads();

    const int r0 = lane & 15, g = lane >> 4, sw = r0 & 7;
    bf16x8 a[4];
#pragma unroll
    for (int kt = 0; kt < 4; ++kt)
        a[kt] = *(const bf16x8*)(&xnL[r0 * 128 + ((kt * 32 + g * 8) ^ (sw << 3))]);

    // c0 = xn @ vW^T + vb : tiles nt = wv*2, wv*2+1
#pragma unroll
    for (int j = 0; j < 2; ++j){
        const int nt = wv * 2 + j;
        const int col = nt * 16 + r0;
        float bv = vb[col];
        f32x4 acc = {bv, bv, bv, bv};
#pragma unroll
        for (int kt = 0; kt < 4; ++kt)
            acc = __builtin_amdgcn_mfma_f32_16x16x32_bf16(
                    a[kt], *(const bf16x8*)(vWb + col * 128 + kt * 32 + g * 8), acc, 0, 0, 0);
#pragma unroll
        for (int q = 0; q < 4; ++q){
            int rr = g * 4 + q;
            c0L[rr * 128 + (col ^ ((rr & 7) << 3))] = f2b(acc[q]);
        }
    }
    __syncthreads();

#pragma unroll
    for (int kt = 0; kt < 4; ++kt)
        a[kt] = *(const bf16x8*)(&c0L[r0 * 128 + ((kt * 32 + g * 8) ^ (sw << 3))]);

    // X0 = c0 @ Wx0^T + b0 : tiles nt = wv*8 .. wv*8+7
#pragma unroll
    for (int j = 0; j < 8; ++j){
        const int nt = wv * 8 + j;
        const int col = nt * 16 + r0;
        float bv = lb[col];
        f32x4 acc = {bv, bv, bv, bv};
#pragma unroll
        for (int kt = 0; kt < 4; ++kt)
            acc = __builtin_amdgcn_mfma_f32_16x16x32_bf16(
                    a[kt], *(const bf16x8*)(wx0b + col * 128 + kt * 32 + g * 8), acc, 0, 0, 0);
#pragma unroll
        for (int q = 0; q < 4; ++q)
            X0F[(rowbase + g * 4 + q) * 512 + col] = acc[q];
    }
}

// ---------- fused 2-layer LSTM, layer-pipelined (65 phases) ----------
// grid 42, block 512 (8 waves, 2/SIMD). 16 batch rows/block.
// Phase ph: L0(t=ph) [ph<64] CONCURRENT WITH L1(t=ph-1) [ph>0].
// Wh0+Wh1 register/AGPR-resident (128); Wx1 in 128KB LDS (swizzled, addresses
// hoisted). One barrier/phase. X0 prefetch into dead acc via running pointers.
__global__ __launch_bounds__(512, 2) void lstm_f2(
    const float* __restrict__ X0, const ushort_t* __restrict__ Wh0,
    const ushort_t* __restrict__ Wx1, const ushort_t* __restrict__ Wh1,
    const float* __restrict__ lb, ushort_t* __restrict__ outB)
{
    extern __shared__ ushort_t smem[];
    ushort_t* hbuf = smem;
    ushort_t* wxs  = smem + 8192;

    const int tid = threadIdx.x;
    const int wid = tid >> 6, lane = tid & 63;
    const int r0 = lane & 15, g = lane >> 4;
    const int sw = r0 & 7;
    const int bcb = blockIdx.x * 16;
    const float K1 = 1.44269504f, K2 = 2.88539008f;

    for (int i = tid; i < 8192; i += 512) hbuf[i] = 0;
    for (int idx = tid; idx < 8192; idx += 512){
        int col = idx >> 4, c = idx & 15;
        *(bf16x8*)(wxs + col * 128 + ((c ^ (col & 7)) << 3)) =
            *(const bf16x8*)(Wx1 + col * 128 + c * 8);
    }

    bf16x8 wh0[4][4], wh1[4][4];
#pragma unroll
    for (int t4 = 0; t4 < 4; ++t4){
        const int cb = t4 * 128 + wid * 16;
#pragma unroll
        for (int kt = 0; kt < 4; ++kt){
            wh0[t4][kt] = *(const bf16x8*)(Wh0 + (cb + r0) * 128 + kt * 32 + g * 8);
            wh1[t4][kt] = *(const bf16x8*)(Wh1 + (cb + r0) * 128 + kt * 32 + g * 8);
        }
    }
    float b1v[4];
#pragma unroll
    for (int t4 = 0; t4 < 4; ++t4) b1v[t4] = lb[512 + t4 * 128 + wid * 16 + r0];

    const char* adr[4];
#pragma unroll
    for (int kt = 0; kt < 4; ++kt)
        adr[kt] = (const char*)hbuf + r0 * 256 + (((kt * 32 + g * 8) ^ (sw << 3)) << 1);
    char* wrq[4];
#pragma unroll
    for (int q = 0; q < 4; ++q){
        int row = g * 4 + q;
        wrq[q] = (char*)hbuf + row * 256 + (((wid * 16 + r0) ^ ((row & 7) << 3)) << 1);
    }
    const char* wxp[4][2];
    {
        const int e = (sw >> 2) * 64;
#pragma unroll
        for (int t4 = 0; t4 < 4; ++t4){
            const char* base = (const char*)wxs
                + (t4 * 128 + wid * 16 + r0) * 256 + ((g ^ (sw & 3)) * 16);
            wxp[t4][0] = base + e;
            wxp[t4][1] = base + (64 - e);
        }
    }
    const char* xp[4];
#pragma unroll
    for (int q = 0; q < 4; ++q)
        xp[q] = (const char*)(X0 + (bcb + g * 4 + q) * 4096 + wid * 16 + r0) + 2048;
    int tnn = 1;

    float c0[4] = {0,0,0,0}, c1[4] = {0,0,0,0};

    f32x4 acc[4];
#pragma unroll
    for (int t4 = 0; t4 < 4; ++t4)
#pragma unroll
        for (int q = 0; q < 4; ++q)
            acc[t4][q] = *(const float*)(xp[q] - 2048 + t4 * 512);

    __syncthreads();

#pragma unroll 1
    for (int tt = 0; tt < 32; ++tt){
#pragma unroll
        for (int pp = 0; pp < 2; ++pp){
            const int ph = tt * 2 + pp;
            const int RDO = (pp ^ 1) * 4096;
            const int WRO = pp * 4096;

            bf16x8 a0[4], ah[4];
#pragma unroll
            for (int kt = 0; kt < 4; ++kt){
                a0[kt] = *(const bf16x8*)(adr[kt] + RDO);
                ah[kt] = *(const bf16x8*)(adr[kt] + 8192 + RDO);
            }

#pragma unroll
            for (int kt = 0; kt < 4; ++kt)
#pragma unroll
                for (int t4 = 0; t4 < 4; ++t4)
                    acc[t4] = __builtin_amdgcn_mfma_f32_16x16x32_bf16(a0[kt], wh0[t4][kt], acc[t4], 0, 0, 0);

#pragma unroll
            for (int q = 0; q < 4; ++q){
                float iv = acc[0][q], fv = acc[1][q], gv = acc[2][q], ov = acc[3][q];
                float af = 1.f + __builtin_amdgcn_exp2f(-K1 * fv);
                float ai = 1.f + __builtin_amdgcn_exp2f(-K1 * iv);
                float bg = 1.f + __builtin_amdgcn_exp2f( K2 * gv);
                float cn = c0[q] * __builtin_amdgcn_rcpf(af)
                         + (bg - 2.f) * __builtin_amdgcn_rcpf(ai * bg);
                c0[q] = cn;
                float ao = 1.f + __builtin_amdgcn_exp2f(-K1 * ov);
                float bc = 1.f + __builtin_amdgcn_exp2f( K2 * cn);
                float hv = (bc - 2.f) * __builtin_amdgcn_rcpf(ao * bc);
                *(ushort_t*)(wrq[q] + WRO) = f2b(hv);
            }

            if (ph > 0){
                f32x4 accB[4];
#pragma unroll
                for (int t4 = 0; t4 < 4; ++t4){
                    f32x4 tmp = {b1v[t4], b1v[t4], b1v[t4], b1v[t4]};
                    accB[t4] = tmp;
                }
#pragma unroll
                for (int kt = 0; kt < 4; ++kt)
#pragma unroll
                    for (int t4 = 0; t4 < 4; ++t4){
                        bf16x8 wx = *(const bf16x8*)(wxp[t4][kt & 1] + ((kt >> 1) << 7));
                        accB[t4] = __builtin_amdgcn_mfma_f32_16x16x32_bf16(a0[kt], wx,          accB[t4], 0, 0, 0);
                        accB[t4] = __builtin_amdgcn_mfma_f32_16x16x32_bf16(ah[kt], wh1[t4][kt], accB[t4], 0, 0, 0);
                    }
#pragma unroll
                for (int q = 0; q < 4; ++q){
                    float iv = accB[0][q], fv = accB[1][q], gv = accB[2][q], ov = accB[3][q];
                    float af = 1.f + __builtin_amdgcn_exp2f(-K1 * fv);
                    float ai = 1.f + __builtin_amdgcn_exp2f(-K1 * iv);
                    float bg = 1.f + __builtin_amdgcn_exp2f( K2 * gv);
                    float cn = c1[q] * __builtin_amdgcn_rcpf(af)
                             + (bg - 2.f) * __builtin_amdgcn_rcpf(ai * bg);
                    c1[q] = cn;
                    float ao = 1.f + __builtin_amdgcn_exp2f(-K1 * ov);
                    float bc = 1.f + __builtin_amdgcn_exp2f( K2 * cn);
                    float hv = (bc - 2.f) * __builtin_amdgcn_rcpf(ao * bc);
                    *(ushort_t*)(wrq[q] + 8192 + WRO) = f2b(hv);
                    if (ph >= 57){
                        int row = g * 4 + q;
                        outB[((bcb + row) * 8 + ((ph - 1) & 7)) * 128 + wid * 16 + r0] = f2b(hv);
                    }
                }
            }

            if (ph < 63){
#pragma unroll
                for (int t4 = 0; t4 < 4; ++t4)
#pragma unroll
                    for (int q = 0; q < 4; ++q)
                        acc[t4][q] = *(const float*)(xp[q] + t4 * 512);
                long d = (tnn == 7) ? -14336L : 2048L;
                tnn = (tnn == 7) ? 0 : tnn + 1;
#pragma unroll
                for (int q = 0; q < 4; ++q) xp[q] += d;
            }
            __syncthreads();
        }
    }

    // epilogue phase ph = 64: L1 only (t = 63)
    {
        bf16x8 a0[4], ah[4];
#pragma unroll
        for (int kt = 0; kt < 4; ++kt){
            a0[kt] = *(const bf16x8*)(adr[kt] + 4096);
            ah[kt] = *(const bf16x8*)(adr[kt] + 8192 + 4096);
        }
        f32x4 acc2[4];
#pragma unroll
        for (int t4 = 0; t4 < 4; ++t4){
            f32x4 tmp = {b1v[t4], b1v[t4], b1v[t4], b1v[t4]};
            acc2[t4] = tmp;
        }
#pragma unroll
        for (int kt = 0; kt < 4; ++kt)
#pragma unroll
            for (int t4 = 0; t4 < 4; ++t4){
                bf16x8 wx = *(const bf16x8*)(wxp[t4][kt & 1] + ((kt >> 1) << 7));
                acc2[t4] = __builtin_amdgcn_mfma_f32_16x16x32_bf16(a0[kt], wx,          acc2[t4], 0, 0, 0);
                acc2[t4] = __builtin_amdgcn_mfma_f32_16x16x32_bf16(ah[kt], wh1[t4][kt], acc2[t4], 0, 0, 0);
            }
#pragma unroll
        for (int q = 0; q < 4; ++q){
            float iv = acc2[0][q], fv = acc2[1][q], gv = acc2[2][q], ov = acc2[3][q];
            float af = 1.f + __builtin_amdgcn_exp2f(-K1 * fv);
            float ai = 1.f + __builtin_amdgcn_exp2f(-K1 * iv);
            float bg = 1.f + __builtin_amdgcn_exp2f( K2 * gv);
            float cn = c1[q] * __builtin_amdgcn_rcpf(af)
                     + (bg - 2.f) * __builtin_amdgcn_rcpf(ai * bg);
            float ao = 1.f + __builtin_amdgcn_exp2f(-K1 * ov);
            float bc = 1.f + __builtin_amdgcn_exp2f( K2 * cn);
            float hv = (bc - 2.f) * __builtin_amdgcn_rcpf(ao * bc);
            int row = g * 4 + q;
            outB[((bcb + row) * 8 + 7) * 128 + wid * 16 + r0] = f2b(hv);
        }
    }
}

// ---------- fused tail: conv1d(SAME,K=3) -> ssm -> outp(+resid xn) -> proj ----------
// grid 336, block 256 (4 waves). Block owns 16 rows; col-tiles split 2/wave.
// Serial MFMA depth per wave: 48 (vs 184 in the 84-block version).
__global__ __launch_bounds__(256) void tail_k(
    const ushort_t* __restrict__ ls, const ushort_t* __restrict__ cWk,
    const float* __restrict__ cbias, const ushort_t* __restrict__ sW,
    const float* __restrict__ sbias, const ushort_t* __restrict__ oW,
    const float* __restrict__ obias, const float* __restrict__ xnF,
    const ushort_t* __restrict__ pW, const float* __restrict__ pbias,
    float* __restrict__ out)
{
    __shared__ ushort_t bufA[2048];
    __shared__ ushort_t bufB[2048];
    const int tid = threadIdx.x;
    const int wv = tid >> 6, lane = tid & 63;
    const int r0 = lane & 15, g = lane >> 4;
    const int rowbase = blockIdx.x * 16;

    // ---- conv: 2 col-tiles per wave ----
    {
        const int n = r0 & 7;
        bf16x8 a[3][4];
#pragma unroll
        for (int k = 0; k < 3; ++k){
            bool valid = (n + k >= 1) && (n + k <= 8);
            const ushort_t* ap = ls + (rowbase + r0 + k - 1) * 128 + g * 8;
#pragma unroll
            for (int kt = 0; kt < 4; ++kt){
                bf16x8 z = {0,0,0,0,0,0,0,0};
                a[k][kt] = valid ? *(const bf16x8*)(ap + kt * 32) : z;
            }
        }
#pragma unroll
        for (int j = 0; j < 2; ++j){
            const int nt = wv * 2 + j;
            const int col = nt * 16 + r0;
            float bv = cbias[col];
            f32x4 acc = {bv, bv, bv, bv};
#pragma unroll
            for (int k = 0; k < 3; ++k)
#pragma unroll
                for (int kt = 0; kt < 4; ++kt)
                    acc = __builtin_amdgcn_mfma_f32_16x16x32_bf16(
                            a[k][kt], *(const bf16x8*)(cWk + k * 16384 + col * 128 + kt * 32 + g * 8),
                            acc, 0, 0, 0);
#pragma unroll
            for (int q = 0; q < 4; ++q){
                int row = g * 4 + q;
                bufA[row * 128 + (col ^ ((row & 7) << 3))] = f2b(acc[q]);
            }
        }
    }
    __syncthreads();
    // ---- ssm: bufA -> bufB (2 tiles/wave) ----
    {
        bf16x8 a[4];
#pragma unroll
        for (int kt = 0; kt < 4; ++kt)
            a[kt] = *(const bf16x8*)(&bufA[r0 * 128 + ((kt * 32 + g * 8) ^ ((r0 & 7) << 3))]);
#pragma unroll
        for (int j = 0; j < 2; ++j){
            const int nt = wv * 2 + j;
            const int col = nt * 16 + r0;
            float bv = sbias[col];
            f32x4 acc = {bv, bv, bv, bv};
#pragma unroll
            for (int kt = 0; kt < 4; ++kt)
                acc = __builtin_amdgcn_mfma_f32_16x16x32_bf16(
                        a[kt], *(const bf16x8*)(sW + col * 128 + kt * 32 + g * 8), acc, 0, 0, 0);
#pragma unroll
            for (int q = 0; q < 4; ++q){
                int row = g * 4 + q;
                bufB[row * 128 + (col ^ ((row & 7) << 3))] = f2b(acc[q]);
            }
        }
    }
    __syncthreads();
    // ---- outp + resid: bufB -> bufA (2 tiles/wave) ----
    {
        bf16x8 a[4];
#pragma unroll
        for (int kt = 0; kt < 4; ++kt)
            a[kt] = *(const bf16x8*)(&bufB[r0 * 128 + ((kt * 32 + g * 8) ^ ((r0 & 7) << 3))]);
#pragma unroll
        for (int j = 0; j < 2; ++j){
            const int nt = wv * 2 + j;
            const int col = nt * 16 + r0;
            float bv = obias[col];
            f32x4 acc = {bv, bv, bv, bv};
#pragma unroll
            for (int kt = 0; kt < 4; ++kt)
                acc = __builtin_amdgcn_mfma_f32_16x16x32_bf16(
                        a[kt], *(const bf16x8*)(oW + col * 128 + kt * 32 + g * 8), acc, 0, 0, 0);
#pragma unroll
            for (int q = 0; q < 4; ++q){
                int row = g * 4 + q;
                float v = acc[q] + xnF[(rowbase + row) * 128 + col];
                bufA[row * 128 + (col ^ ((row & 7) << 3))] = f2b(v);
            }
        }
    }
    __syncthreads();
    // ---- proj: bufA -> out (6 col-tiles over 4 waves) ----
    {
        bf16x8 a[4];
#pragma unroll
        for (int kt = 0; kt < 4; ++kt)
            a[kt] = *(const bf16x8*)(&bufA[r0 * 128 + ((kt * 32 + g * 8) ^ ((r0 & 7) << 3))]);
        for (int nt = wv; nt < 6; nt += 4){
            const int col = nt * 16 + r0;
            float bv = pbias[col];
            f32x4 acc = {bv, bv, bv, bv};
#pragma unroll
            for (int kt = 0; kt < 4; ++kt)
                acc = __builtin_amdgcn_mfma_f32_16x16x32_bf16(
                        a[kt], *(const bf16x8*)(pW + col * 128 + kt * 32 + g * 8), acc, 0, 0, 0);
#pragma unroll
            for (int q = 0; q < 4; ++q)
                out[(rowbase + g * 4 + q) * 96 + col] = acc[q];
        }
    }
}

// ---------- launch ----------
extern "C" void kernel_launch(void* const* d_in, const int* in_sizes, int n_in,
                              void* d_out, int out_size, void* d_ws, size_t ws_size,
                              hipStream_t stream)
{
    const float* x   = (const float*)d_in[0];
    const float* eW  = (const float*)d_in[1];
    const float* eb  = (const float*)d_in[2];
    const float* lng = (const float*)d_in[3];
    const float* lnb = (const float*)d_in[4];
    const float* vW  = (const float*)d_in[9];
    const float* vb  = (const float*)d_in[10];
    const float* Wx  = (const float*)d_in[11];
    const float* Wh  = (const float*)d_in[12];
    const float* lb  = (const float*)d_in[13];
    const float* cW  = (const float*)d_in[14];
    const float* cb_ = (const float*)d_in[15];
    const float* sW  = (const float*)d_in[16];
    const float* sb  = (const float*)d_in[17];
    const float* oW  = (const float*)d_in[18];
    const float* ob  = (const float*)d_in[19];
    const float* pW  = (const float*)d_in[20];
    const float* pb  = (const float*)d_in[21];

    char* ws = (char*)d_ws;
    float*    xnF = (float*)   (ws + 0);          // 5376x128 f32   (2.75 MB)
    float*    X0F = (float*)   (ws + 5505024);    // 5376x512 f32   (11 MB)
    ushort_t* lsB = (ushort_t*)(ws + 16515072);   // lstm out bf16  (1.38 MB)
    ushort_t* wb  = (ushort_t*)(ws + 17891328);   // bf16 weights   (0.75 MB)
    float*    xT  = (float*)   (ws + 18874368);   // x transposed [b][c][l] (344 KB)

    hipFuncSetAttribute((const void*)lstm_f2,
                        hipFuncAttributeMaxDynamicSharedMemorySize, 147456);

    prep_k<<<dim3(256, 10), 256, 0, stream>>>(vW, Wx, Wh, cW, sW, oW, pW, x, wb, xT);
    // fused embed+LN -> c0 -> X0 (4-wave blocks, work split across waves)
    head_k<<<336, 256, 0, stream>>>(xT, eW, eb, lng, lnb, wb + 0, vb, wb + 16384, lb,
                                    xnF, X0F);
    // fused layer-pipelined 2-layer recurrence (65 phases, one barrier each)
    lstm_f2<<<42, 512, 147456, stream>>>(X0F, wb + 81920, wb + 147456, wb + 212992,
                                         lb, lsB);
    // tail: 16 rows/block, col-tiles split across 4 waves
    tail_k<<<336, 256, 0, stream>>>(lsB, wb + 278528, cb_, wb + 327680, sb,
                                    wb + 344064, ob, xnF, wb + 360448, pb, (float*)d_out);
}